// Round 7
// baseline (100.251 us; speedup 1.0000x reference)
//
#include <hip/hip_runtime.h>
#include <math.h>

#define T_ 16
#define B_ 16
#define C_ 8
#define H_ 128
#define W_ 128
#define HW_ (H_*W_)
#define CHW_ (C_*HW_)
#define NSL 16                       // K1a: 16 slices of 8 rows per (t,b)
#define NV 19                        // 0..7 sumc, 8..15 maxc, 16 dsum, 17 m1(unused in K1a), 18 m2

__device__ __forceinline__ float wave_sum(float v){
    #pragma unroll
    for (int o=32;o>0;o>>=1) v += __shfl_down(v,o,64);
    return v;
}
__device__ __forceinline__ float wave_max(float v){
    #pragma unroll
    for (int o=32;o>0;o>>=1) v = fmaxf(v,__shfl_down(v,o,64));
    return v;
}

// ---------------- K1a: barrier-free streaming stats + y-field ----------------
// Block = (tb, 8-row slice). No LDS/barriers until the final 19-value reduce.
// Writes y = sum_c x to yfield (for the m1 kernel) and 18 partial stats.
__global__ __launch_bounds__(256, 4) void stats_stream_kernel(
    const float* __restrict__ events, float* __restrict__ partials,
    float* __restrict__ yfield)
{
    int bid = blockIdx.x;
    int s   = bid & 15;
    int tb  = bid >> 4;
    int t   = tb >> 4;               // / B_
    int tid = threadIdx.x;
    int r   = tid >> 5;              // 0..7
    int c0  = (tid & 31) * 4;
    int gh  = s*8 + r;

    const float* frame = events + (size_t)tb*CHW_ + gh*W_ + c0;
    const float* prev  = frame - (size_t)B_*CHW_;   // deref'd only when t>0

    float4 xv[C_];
    #pragma unroll
    for (int c=0;c<C_;c++) xv[c] = *reinterpret_cast<const float4*>(frame + c*HW_);

    float dsum = 0.f;
    if (t > 0){
        #pragma unroll
        for (int c=0;c<C_;c++){
            float4 p = *reinterpret_cast<const float4*>(prev + c*HW_);
            float4 x = xv[c];
            dsum += fabsf(x.x-p.x)+fabsf(x.y-p.y)
                  + fabsf(x.z-p.z)+fabsf(x.w-p.w);
        }
    }

    float sumc[C_], maxc[C_];
    float4 y; y.x=0.f; y.y=0.f; y.z=0.f; y.w=0.f;
    float q0=0.f,q1=0.f,q2=0.f,q3=0.f;
    #pragma unroll
    for (int c=0;c<C_;c++){
        float4 x = xv[c];
        y.x+=x.x; y.y+=x.y; y.z+=x.z; y.w+=x.w;
        q0=fmaf(x.x,x.x,q0); q1=fmaf(x.y,x.y,q1);
        q2=fmaf(x.z,x.z,q2); q3=fmaf(x.w,x.w,q3);
        sumc[c] = (x.x+x.y)+(x.z+x.w);
        maxc[c] = fmaxf(fmaxf(x.x,x.y),fmaxf(x.z,x.w));
    }
    float cnt0 = (c0==0)      ? 2.f : 3.f;
    float cnt3 = (c0+3==W_-1) ? 2.f : 3.f;
    float cnth = (gh==0 || gh==H_-1) ? 2.f : 3.f;
    float m2 = cnth * (q0*cnt0 + (q1+q2)*3.f + q3*cnt3);

    *reinterpret_cast<float4*>(yfield + (size_t)tb*HW_ + gh*W_ + c0) = y;

    float vals[NV];
    #pragma unroll
    for (int c=0;c<C_;c++){ vals[c]=sumc[c]; vals[8+c]=maxc[c]; }
    vals[16]=dsum; vals[17]=0.f; vals[18]=m2;

    __shared__ float red[4][NV];
    int lane = tid & 63, wv = tid >> 6;
    #pragma unroll
    for (int i=0;i<NV;i++){
        float rr = (i>=8 && i<16) ? wave_max(vals[i]) : wave_sum(vals[i]);
        if (lane==0) red[wv][i] = rr;
    }
    __syncthreads();
    if (tid < NV){
        float a = red[0][tid], b2 = red[1][tid], c = red[2][tid], d = red[3][tid];
        float rr = (tid>=8 && tid<16) ? fmaxf(fmaxf(a,b2),fmaxf(c,d)) : ((a+b2)+(c+d));
        partials[((size_t)tb*NSL + s)*NV + tid] = rr;
    }
}

// ---------------- K1b: m1 = sum(s1^2) from the y-field ----------------
// Block = (tb, 16-row slice); 3x3 zero-padded box filter of y.
__global__ __launch_bounds__(256) void m1_kernel(
    const float* __restrict__ yfield, float* __restrict__ m1p)
{
    int bid = blockIdx.x;            // tb*8 + s
    int s   = bid & 7;
    int tb  = bid >> 3;
    int h0  = s*16;
    int tid = threadIdx.x;
    __shared__ float yb[18][W_];     // rows h0-1 .. h0+16

    const float* yf = yfield + (size_t)tb*HW_;
    for (int i = tid; i < 18*32; i += 256){
        int rr = i >> 5, cc = (i & 31) * 4;
        int gh = h0 - 1 + rr;
        float4 v; v.x=0.f; v.y=0.f; v.z=0.f; v.w=0.f;
        if (gh >= 0 && gh < H_) v = *reinterpret_cast<const float4*>(yf + gh*W_ + cc);
        *reinterpret_cast<float4*>(&yb[rr][cc]) = v;
    }
    __syncthreads();

    float m1 = 0.f;
    {
        int w  = tid & 127;
        int rg = tid >> 7;
        bool hasL = (w>0), hasR = (w<W_-1);
        int base = rg*8;
        const float* row;
        row = yb[base];   float a0 = row[w] + (hasL?row[w-1]:0.f) + (hasR?row[w+1]:0.f);
        row = yb[base+1]; float a1 = row[w] + (hasL?row[w-1]:0.f) + (hasR?row[w+1]:0.f);
        #pragma unroll
        for (int i=0;i<8;i++){
            row = yb[base+2+i];
            float a2 = row[w] + (hasL?row[w-1]:0.f) + (hasR?row[w+1]:0.f);
            float s1 = a0 + a1 + a2;
            m1 = fmaf(s1, s1, m1);
            a0 = a1; a1 = a2;
        }
    }
    m1 = wave_sum(m1);
    __shared__ float red2[4];
    int lane = tid & 63, wv = tid >> 6;
    if (lane==0) red2[wv] = m1;
    __syncthreads();
    if (tid==0) m1p[bid] = (red2[0]+red2[1])+(red2[2]+red2[3]);
}

// ---------------- K2: combine partials -> beta[t,b,c], thr[t,b] ----------------
__global__ __launch_bounds__(64) void combine_kernel(
    const float* __restrict__ partials,
    const float* __restrict__ m1p,
    const float* __restrict__ att_w1,   // (1,16) row-major
    const float* __restrict__ att_w2,   // (8,1)
    const float* __restrict__ dwp, const float* __restrict__ twp,
    const float* __restrict__ mwp,
    float* __restrict__ beta_out, float* __restrict__ thr_out,
    float* __restrict__ zeropad)
{
    int tb = blockIdx.x;
    int t  = tb / B_;
    int i  = threadIdx.x;
    if (tb == 0 && i < 16) zeropad[i] = 0.f;   // 64B zero region for lif halo loads
    __shared__ float v[NV];
    if (i < NV){
        if (i == 17){
            const float* mp = m1p + (size_t)tb*8;
            float acc = 0.f;
            #pragma unroll
            for (int k=0;k<8;k++) acc += mp[k];
            v[17] = acc;
        } else {
            const float* p = partials + (size_t)tb*NSL*NV;
            bool mx = (i>=8 && i<16);
            float acc = p[i];
            #pragma unroll
            for (int k=1;k<NSL;k++){
                float x = p[k*NV + i];
                acc = mx ? fmaxf(acc, x) : (acc + x);
            }
            v[i] = acc;
        }
    }
    __syncthreads();
    if (i == 0){
        float h1 = 0.f;
        for (int c=0;c<C_;c++) h1 += v[8+c] * att_w1[c];
        for (int c=0;c<C_;c++) h1 += (v[c]/(float)HW_) * att_w1[C_+c];
        h1 = fmaxf(h1, 0.f);
        float total = 0.f;
        for (int c=0;c<C_;c++) total += v[c];
        float density  = total / (float)CHW_;
        float temporal = (t==0) ? 0.f : v[16] / (float)CHW_;
        float motion   = (v[18] - v[17]/72.f) / 71.f / (float)HW_;
        float z = dwp[0]*density + twp[0]*temporal + mwp[0]*motion;
        float adj = 2.f / (1.f + expf(-z));
        thr_out[tb] = 1.f + adj;
        for (int c=0;c<C_;c++){
            float sg = 1.f / (1.f + expf(-(h1 * att_w2[c])));
            beta_out[tb*C_ + c] = 0.5f + 0.45f*sg;
        }
    }
}

// ---------------- K3: depthwise conv + sequential LIF (R3 gload_lds version) ----------------
__device__ __forceinline__ void gload16(const float* src, float* lds_dst){
    __builtin_amdgcn_global_load_lds(
        (const __attribute__((address_space(1))) unsigned int*)src,
        (__attribute__((address_space(3))) unsigned int*)lds_dst, 16, 0, 0);
}

__device__ __forceinline__ float fast_atan(float x){
    float ax = fabsf(x);
    bool inv = ax > 1.f;
    float z  = inv ? __builtin_amdgcn_rcpf(ax) : ax;
    float z2 = z*z;
    float p = -0.0117212f;
    p = fmaf(p, z2,  0.05265332f);
    p = fmaf(p, z2, -0.11643287f);
    p = fmaf(p, z2,  0.19354346f);
    p = fmaf(p, z2, -0.33262347f);
    p = fmaf(p, z2,  0.99997726f);
    p = p * z;
    float r = inv ? (1.57079632679f - p) : p;
    return copysignf(r, x);
}

#define SROWS 10   // staged rows: h0-1 .. h0+8

__global__ __launch_bounds__(256, 8) void lif_kernel(
    const float* __restrict__ events,
    const float* __restrict__ conv_w,   // (C,1,3,3)
    const float* __restrict__ beta,     // [T*B*C]
    const float* __restrict__ thr,      // [T*B]
    const float* __restrict__ zeropad,  // >=16B of zeros
    float* __restrict__ out)
{
    int bid  = blockIdx.x;
    int hblk = bid & 15;                // 16 row-blocks of 8 rows
    int bc   = bid >> 4;                // 0..127
    int b = bc >> 3, c = bc & 7;
    int h0 = hblk * 8;
    int tid = threadIdx.x;
    int wv  = tid >> 6;                 // wave id 0..3

    float wk[9];
    #pragma unroll
    for (int k=0;k<9;k++) wk[k] = conv_w[c*9 + k];

    __shared__ float lds[2][SROWS*W_];  // 2 x 10 x 128 floats = 10 KiB

    int idxA = tid,        rowA = idxA >> 5, colA = (idxA & 31) * 4;
    int idxB = 256 + tid,  rowB = idxB >> 5, colB = (idxB & 31) * 4;
    int ghA = h0 - 1 + rowA;
    int ghB = h0 - 1 + rowB;
    bool okA = (ghA >= 0) && (ghA < H_);
    bool okB = (ghB >= 0) && (ghB < H_);
    const float* baseFrame = events + ((size_t)(b * C_) + c) * HW_;
    const float* srcA0 = okA ? (baseFrame + ghA*W_ + colA) : zeropad;
    const float* srcB0 = okB ? (baseFrame + ghB*W_ + colB) : zeropad;
    const size_t tstep = (size_t)B_ * CHW_;
    size_t stepA = okA ? tstep : 0;
    size_t stepB = okB ? tstep : 0;

    int w  = tid & 127;
    int rg = tid >> 7;
    int rbase = rg * 4;
    int wl = (w > 0)    ? w-1 : 0;
    int wr = (w < W_-1) ? w+1 : W_-1;
    bool hasL = (w > 0), hasR = (w < W_-1);

    float v[4];
    #pragma unroll
    for (int i=0;i<4;i++) v[i] = 0.f;

    gload16(srcA0, &lds[0][wv*256]);
    if (wv == 0) gload16(srcB0, &lds[0][1024]);

    const float* bp = beta + (b*C_ + c);
    const float* tp = thr + b;
    float bv = bp[0];
    float th = tp[0];

    for (int t = 0; t < T_; ++t){
        int cur = t & 1, nxt = cur ^ 1;
        __syncthreads();

        if (t + 1 < T_){
            gload16(srcA0 + (size_t)(t+1)*stepA, &lds[nxt][wv*256]);
            if (wv == 0) gload16(srcB0 + (size_t)(t+1)*stepB, &lds[nxt][1024]);
        }
        float bvn = (t+1 < T_) ? bp[(size_t)(t+1)*B_*C_] : 0.f;
        float thn = (t+1 < T_) ? tp[(size_t)(t+1)*B_]    : 0.f;

        const float* L = &lds[cur][0];
        float omb = 1.f - bv;
        float* op = out + ((size_t)(t*B_+b)*C_ + c)*HW_ + h0*W_;

        const float* row0 = L + rbase*W_;
        const float* row1 = row0 + W_;
        float la = hasL ? row0[wl] : 0.f;  float ma = row0[w];  float ra = hasR ? row0[wr] : 0.f;
        float lb = hasL ? row1[wl] : 0.f;  float mb = row1[w];  float rb = hasR ? row1[wr] : 0.f;

        #pragma unroll
        for (int i=0;i<4;i++){
            const float* rowc = L + (rbase+2+i)*W_;
            float lc = hasL ? rowc[wl] : 0.f;
            float mc = rowc[w];
            float rc = hasR ? rowc[wr] : 0.f;
            float wi = wk[0]*la + wk[1]*ma + wk[2]*ra
                     + wk[3]*lb + wk[4]*mb + wk[5]*rb
                     + wk[6]*lc + wk[7]*mc + wk[8]*rc;
            float vv = fmaf(bv, v[i], omb*wi);
            float sp = fast_atan(2.f*(vv - th))*0.5f + 0.5f;
            op[(rbase+i)*W_ + w] = mb * sp;
            v[i] = (1.f - sp) * vv;
            la=lb; ma=mb; ra=rb; lb=lc; mb=mc; rb=rc;
        }
        __syncthreads();

        bv = bvn; th = thn;
    }
}

extern "C" void kernel_launch(void* const* d_in, const int* in_sizes, int n_in,
                              void* d_out, int out_size, void* d_ws, size_t ws_size,
                              hipStream_t stream)
{
    const float* events = (const float*)d_in[0];
    const float* conv_w = (const float*)d_in[1];
    const float* att_w1 = (const float*)d_in[2];
    const float* att_w2 = (const float*)d_in[3];
    const float* dwp    = (const float*)d_in[4];
    const float* twp    = (const float*)d_in[5];
    const float* mwp    = (const float*)d_in[6];
    float* out = (float*)d_out;

    float* ws       = (float*)d_ws;
    float* partials = ws;                                  // 256*16*19
    float* m1p      = partials + (size_t)T_*B_*NSL*NV;     // 2048
    float* beta     = m1p + (size_t)T_*B_*8;               // 2048
    float* thr      = beta + (size_t)T_*B_*C_;             // 256
    float* zeropad  = thr + T_*B_;                         // 16
    float* yfield   = zeropad + 16;                        // T*B*H*W = 4.19M floats

    stats_stream_kernel<<<T_*B_*NSL, 256, 0, stream>>>(events, partials, yfield);
    m1_kernel          <<<T_*B_*8,   256, 0, stream>>>(yfield, m1p);
    combine_kernel     <<<T_*B_,     64,  0, stream>>>(partials, m1p, att_w1, att_w2,
                                                       dwp, twp, mwp, beta, thr, zeropad);
    lif_kernel         <<<B_*C_*16,  256, 0, stream>>>(events, conv_w, beta, thr, zeropad, out);
}

// Round 8
// 95.372 us; speedup vs baseline: 1.0512x; 1.0512x over previous
//
#include <hip/hip_runtime.h>
#include <math.h>

#define T_ 16
#define B_ 16
#define C_ 8
#define H_ 128
#define W_ 128
#define HW_ (H_*W_)
#define CHW_ (C_*HW_)
#define TC 4                          // t-chunk length (4 chunks)
#define NSL 16                        // 16 slices of 8 rows

__device__ __forceinline__ float wave_sum(float v){
    #pragma unroll
    for (int o=32;o>0;o>>=1) v += __shfl_down(v,o,64);
    return v;
}
__device__ __forceinline__ float wave_max(float v){
    #pragma unroll
    for (int o=32;o>0;o>>=1) v = fmaxf(v,__shfl_down(v,o,64));
    return v;
}

// ---------------- K1a: channel-contiguous, t-chunked stats + y-field ----------------
// Block = (b, 8-row slice, t-chunk). 512 threads = 8 waves; wave c owns channel c:
// per t it reads a CONTIGUOUS 4KB run (8 rows x 128 cols of one channel), keeps the
// previous frame in registers (px) for dsum, computes per-channel sum/max/m2/dsum,
// stages x in LDS so a second pass builds y = sum_c x for the m1 kernel.
__global__ __launch_bounds__(512, 4) void stats_kernel(
    const float* __restrict__ events, float* __restrict__ partials,
    float* __restrict__ yfield)
{
    int bid   = blockIdx.x;            // 1024 blocks
    int chunk = bid & 3;
    int s     = (bid >> 2) & 15;
    int b     = bid >> 6;
    int t0    = chunk * TC;
    int gh0   = s * 8;
    int tid   = threadIdx.x;           // 0..511
    int c     = tid >> 6;              // wave id == channel
    int lane  = tid & 63;

    __shared__ float xs[C_][1024];     // 8 x 4KB = 32 KB

    int lrow  = lane >> 3;             // 0..7
    int lcol0 = (lane & 7) * 16;       // element cols lcol0..lcol0+15
    int gh    = gh0 + lrow;
    float cnth = (gh==0 || gh==H_-1) ? 2.f : 3.f;
    float w0  = (lcol0==0)        ? 2.f : 3.f;   // col 0 weight
    float w15 = (lcol0+15==W_-1)  ? 2.f : 3.f;   // col 127 weight

    const float* base0 = events + (size_t)(t0*B_+b)*CHW_ + c*HW_ + gh*W_ + lcol0;
    const size_t tstep = (size_t)B_ * CHW_;

    float px[16];
    if (t0 > 0){
        const float* pp = base0 - tstep;
        #pragma unroll
        for (int e=0;e<16;e+=4){
            float4 v = *reinterpret_cast<const float4*>(pp + e);
            px[e]=v.x; px[e+1]=v.y; px[e+2]=v.z; px[e+3]=v.w;
        }
    } else {
        #pragma unroll
        for (int e=0;e<16;e++) px[e]=0.f;
    }

    #pragma unroll 1
    for (int tt=0; tt<TC; ++tt){
        int t = t0 + tt;
        const float* src = base0 + (size_t)tt*tstep;

        float cx[16];
        #pragma unroll
        for (int e=0;e<16;e+=4){
            float4 v = *reinterpret_cast<const float4*>(src + e);
            cx[e]=v.x; cx[e+1]=v.y; cx[e+2]=v.z; cx[e+3]=v.w;
        }

        float ssum=0.f, smax=-INFINITY, q=0.f, dsu=0.f;
        #pragma unroll
        for (int e=0;e<16;e++){
            float x = cx[e];
            ssum += x;
            smax = fmaxf(smax, x);
            float w = (e==0) ? w0 : ((e==15) ? w15 : 3.f);
            q = fmaf(w*x, x, q);
            dsu += fabsf(x - px[e]);
            px[e] = x;
        }

        #pragma unroll
        for (int e=0;e<16;e+=4){
            float4 v; v.x=cx[e]; v.y=cx[e+1]; v.z=cx[e+2]; v.w=cx[e+3];
            *reinterpret_cast<float4*>(&xs[c][lane*16 + e]) = v;
        }
        __syncthreads();

        // y pass: 512 threads x 2 pixels, sum over 8 channels
        {
            int p0 = tid * 2;
            float y0=0.f, y1=0.f;
            #pragma unroll
            for (int cc=0; cc<C_; cc++){
                y0 += xs[cc][p0];
                y1 += xs[cc][p0+1];
            }
            float2 yy; yy.x=y0; yy.y=y1;
            *reinterpret_cast<float2*>(yfield + (size_t)(t*B_+b)*HW_ + gh0*W_ + p0) = yy;
        }

        // per-wave (= per-channel) reduce of 4 values
        float rs = wave_sum(ssum);
        float rm = wave_max(smax);
        float rd = wave_sum(dsu);
        float rq = wave_sum(cnth * q);
        if (lane == 0){
            float4 o; o.x=rs; o.y=rm; o.z=rd; o.w=rq;
            *reinterpret_cast<float4*>(
                partials + (((size_t)(t*B_+b)*NSL + s)*C_ + c)*4) = o;
        }
        __syncthreads();   // protect xs before next t overwrites
    }
}

// ---------------- K1b: m1 = sum(s1^2) from the y-field ----------------
__global__ __launch_bounds__(256) void m1_kernel(
    const float* __restrict__ yfield, float* __restrict__ m1p)
{
    int bid = blockIdx.x;            // tb*8 + s
    int s   = bid & 7;
    int tb  = bid >> 3;
    int h0  = s*16;
    int tid = threadIdx.x;
    __shared__ float yb[18][W_];     // rows h0-1 .. h0+16

    const float* yf = yfield + (size_t)tb*HW_;
    for (int i = tid; i < 18*32; i += 256){
        int rr = i >> 5, cc = (i & 31) * 4;
        int gh = h0 - 1 + rr;
        float4 v; v.x=0.f; v.y=0.f; v.z=0.f; v.w=0.f;
        if (gh >= 0 && gh < H_) v = *reinterpret_cast<const float4*>(yf + gh*W_ + cc);
        *reinterpret_cast<float4*>(&yb[rr][cc]) = v;
    }
    __syncthreads();

    float m1 = 0.f;
    {
        int w  = tid & 127;
        int rg = tid >> 7;
        bool hasL = (w>0), hasR = (w<W_-1);
        int base = rg*8;
        const float* row;
        row = yb[base];   float a0 = row[w] + (hasL?row[w-1]:0.f) + (hasR?row[w+1]:0.f);
        row = yb[base+1]; float a1 = row[w] + (hasL?row[w-1]:0.f) + (hasR?row[w+1]:0.f);
        #pragma unroll
        for (int i=0;i<8;i++){
            row = yb[base+2+i];
            float a2 = row[w] + (hasL?row[w-1]:0.f) + (hasR?row[w+1]:0.f);
            float s1 = a0 + a1 + a2;
            m1 = fmaf(s1, s1, m1);
            a0 = a1; a1 = a2;
        }
    }
    m1 = wave_sum(m1);
    __shared__ float red2[4];
    int lane = tid & 63, wv = tid >> 6;
    if (lane==0) red2[wv] = m1;
    __syncthreads();
    if (tid==0) m1p[bid] = (red2[0]+red2[1])+(red2[2]+red2[3]);
}

// ---------------- K2: combine partials -> beta[t,b,c], thr[t,b] ----------------
__global__ __launch_bounds__(64) void combine_kernel(
    const float* __restrict__ partials,   // [tb][16 slices][8 ch][4: sum,max,dsum,m2]
    const float* __restrict__ m1p,        // [tb][8]
    const float* __restrict__ att_w1,     // (1,16) row-major
    const float* __restrict__ att_w2,     // (8,1)
    const float* __restrict__ dwp, const float* __restrict__ twp,
    const float* __restrict__ mwp,
    float* __restrict__ beta_out, float* __restrict__ thr_out,
    float* __restrict__ zeropad)
{
    int tb = blockIdx.x;
    int t  = tb / B_;
    int i  = threadIdx.x;
    if (tb == 0 && i < 16) zeropad[i] = 0.f;   // 64B zero region for lif halo loads
    __shared__ float v[19];
    const float* p = partials + (size_t)tb*NSL*C_*4;
    if (i < 8){                       // sumc[c]
        float acc = 0.f;
        #pragma unroll
        for (int s=0;s<NSL;s++) acc += p[(s*C_ + i)*4 + 0];
        v[i] = acc;
    } else if (i < 16){               // maxc[c]
        int c = i - 8;
        float acc = -INFINITY;
        #pragma unroll
        for (int s=0;s<NSL;s++) acc = fmaxf(acc, p[(s*C_ + c)*4 + 1]);
        v[i] = acc;
    } else if (i == 16){              // dsum
        float acc = 0.f;
        for (int k=0;k<NSL*C_;k++) acc += p[k*4 + 2];
        v[16] = acc;
    } else if (i == 17){              // m1
        const float* mp = m1p + (size_t)tb*8;
        float acc = 0.f;
        #pragma unroll
        for (int k=0;k<8;k++) acc += mp[k];
        v[17] = acc;
    } else if (i == 18){              // m2
        float acc = 0.f;
        for (int k=0;k<NSL*C_;k++) acc += p[k*4 + 3];
        v[18] = acc;
    }
    __syncthreads();
    if (i == 0){
        float h1 = 0.f;
        for (int c=0;c<C_;c++) h1 += v[8+c] * att_w1[c];
        for (int c=0;c<C_;c++) h1 += (v[c]/(float)HW_) * att_w1[C_+c];
        h1 = fmaxf(h1, 0.f);
        float total = 0.f;
        for (int c=0;c<C_;c++) total += v[c];
        float density  = total / (float)CHW_;
        float temporal = (t==0) ? 0.f : v[16] / (float)CHW_;
        float motion   = (v[18] - v[17]/72.f) / 71.f / (float)HW_;
        float z = dwp[0]*density + twp[0]*temporal + mwp[0]*motion;
        float adj = 2.f / (1.f + expf(-z));
        thr_out[tb] = 1.f + adj;
        for (int c=0;c<C_;c++){
            float sg = 1.f / (1.f + expf(-(h1 * att_w2[c])));
            beta_out[tb*C_ + c] = 0.5f + 0.45f*sg;
        }
    }
}

// ---------------- K3: depthwise conv + LIF, nontemporal out-stores ----------------
__device__ __forceinline__ void gload16(const float* src, float* lds_dst){
    __builtin_amdgcn_global_load_lds(
        (const __attribute__((address_space(1))) unsigned int*)src,
        (__attribute__((address_space(3))) unsigned int*)lds_dst, 16, 0, 0);
}

__device__ __forceinline__ float fast_atan(float x){
    float ax = fabsf(x);
    bool inv = ax > 1.f;
    float z  = inv ? __builtin_amdgcn_rcpf(ax) : ax;
    float z2 = z*z;
    float p = -0.0117212f;
    p = fmaf(p, z2,  0.05265332f);
    p = fmaf(p, z2, -0.11643287f);
    p = fmaf(p, z2,  0.19354346f);
    p = fmaf(p, z2, -0.33262347f);
    p = fmaf(p, z2,  0.99997726f);
    p = p * z;
    float r = inv ? (1.57079632679f - p) : p;
    return copysignf(r, x);
}

#define SROWS 10   // staged rows: h0-1 .. h0+8

__global__ __launch_bounds__(256, 8) void lif_kernel(
    const float* __restrict__ events,
    const float* __restrict__ conv_w,   // (C,1,3,3)
    const float* __restrict__ beta,     // [T*B*C]
    const float* __restrict__ thr,      // [T*B]
    const float* __restrict__ zeropad,  // >=16B of zeros
    float* __restrict__ out)
{
    int bid  = blockIdx.x;
    int hblk = bid & 15;                // 16 row-blocks of 8 rows
    int bc   = bid >> 4;                // 0..127
    int b = bc >> 3, c = bc & 7;
    int h0 = hblk * 8;
    int tid = threadIdx.x;
    int wv  = tid >> 6;                 // wave id 0..3

    float wk[9];
    #pragma unroll
    for (int k=0;k<9;k++) wk[k] = conv_w[c*9 + k];

    __shared__ float lds[2][SROWS*W_];  // 2 x 10 x 128 floats = 10 KiB

    int idxA = tid,        rowA = idxA >> 5, colA = (idxA & 31) * 4;
    int idxB = 256 + tid,  rowB = idxB >> 5, colB = (idxB & 31) * 4;
    int ghA = h0 - 1 + rowA;
    int ghB = h0 - 1 + rowB;
    bool okA = (ghA >= 0) && (ghA < H_);
    bool okB = (ghB >= 0) && (ghB < H_);
    const float* baseFrame = events + ((size_t)(b * C_) + c) * HW_;
    const float* srcA0 = okA ? (baseFrame + ghA*W_ + colA) : zeropad;
    const float* srcB0 = okB ? (baseFrame + ghB*W_ + colB) : zeropad;
    const size_t tstep = (size_t)B_ * CHW_;
    size_t stepA = okA ? tstep : 0;
    size_t stepB = okB ? tstep : 0;

    int w  = tid & 127;
    int rg = tid >> 7;
    int rbase = rg * 4;
    int wl = (w > 0)    ? w-1 : 0;
    int wr = (w < W_-1) ? w+1 : W_-1;
    bool hasL = (w > 0), hasR = (w < W_-1);

    float v[4];
    #pragma unroll
    for (int i=0;i<4;i++) v[i] = 0.f;

    gload16(srcA0, &lds[0][wv*256]);
    if (wv == 0) gload16(srcB0, &lds[0][1024]);

    const float* bp = beta + (b*C_ + c);
    const float* tp = thr + b;
    float bv = bp[0];
    float th = tp[0];

    for (int t = 0; t < T_; ++t){
        int cur = t & 1, nxt = cur ^ 1;
        __syncthreads();

        if (t + 1 < T_){
            gload16(srcA0 + (size_t)(t+1)*stepA, &lds[nxt][wv*256]);
            if (wv == 0) gload16(srcB0 + (size_t)(t+1)*stepB, &lds[nxt][1024]);
        }
        float bvn = (t+1 < T_) ? bp[(size_t)(t+1)*B_*C_] : 0.f;
        float thn = (t+1 < T_) ? tp[(size_t)(t+1)*B_]    : 0.f;

        const float* L = &lds[cur][0];
        float omb = 1.f - bv;
        float* op = out + ((size_t)(t*B_+b)*C_ + c)*HW_ + h0*W_;

        const float* row0 = L + rbase*W_;
        const float* row1 = row0 + W_;
        float la = hasL ? row0[wl] : 0.f;  float ma = row0[w];  float ra = hasR ? row0[wr] : 0.f;
        float lb = hasL ? row1[wl] : 0.f;  float mb = row1[w];  float rb = hasR ? row1[wr] : 0.f;

        #pragma unroll
        for (int i=0;i<4;i++){
            const float* rowc = L + (rbase+2+i)*W_;
            float lc = hasL ? rowc[wl] : 0.f;
            float mc = rowc[w];
            float rc = hasR ? rowc[wr] : 0.f;
            float wi = wk[0]*la + wk[1]*ma + wk[2]*ra
                     + wk[3]*lb + wk[4]*mb + wk[5]*rb
                     + wk[6]*lc + wk[7]*mc + wk[8]*rc;
            float vv = fmaf(bv, v[i], omb*wi);
            float sp = fast_atan(2.f*(vv - th))*0.5f + 0.5f;
            __builtin_nontemporal_store(mb * sp, &op[(rbase+i)*W_ + w]);
            v[i] = (1.f - sp) * vv;
            la=lb; ma=mb; ra=rb; lb=lc; mb=mc; rb=rc;
        }
        __syncthreads();

        bv = bvn; th = thn;
    }
}

extern "C" void kernel_launch(void* const* d_in, const int* in_sizes, int n_in,
                              void* d_out, int out_size, void* d_ws, size_t ws_size,
                              hipStream_t stream)
{
    const float* events = (const float*)d_in[0];
    const float* conv_w = (const float*)d_in[1];
    const float* att_w1 = (const float*)d_in[2];
    const float* att_w2 = (const float*)d_in[3];
    const float* dwp    = (const float*)d_in[4];
    const float* twp    = (const float*)d_in[5];
    const float* mwp    = (const float*)d_in[6];
    float* out = (float*)d_out;

    float* ws       = (float*)d_ws;
    float* partials = ws;                                   // 256*16*8*4 = 131072
    float* m1p      = partials + (size_t)T_*B_*NSL*C_*4;    // 2048
    float* beta     = m1p + (size_t)T_*B_*8;                // 2048
    float* thr      = beta + (size_t)T_*B_*C_;              // 256
    float* zeropad  = thr + T_*B_;                          // 16
    float* yfield   = zeropad + 16;                         // T*B*H*W floats

    stats_kernel  <<<B_*NSL*4,  512, 0, stream>>>(events, partials, yfield);
    m1_kernel     <<<T_*B_*8,   256, 0, stream>>>(yfield, m1p);
    combine_kernel<<<T_*B_,     64,  0, stream>>>(partials, m1p, att_w1, att_w2,
                                                  dwp, twp, mwp, beta, thr, zeropad);
    lif_kernel    <<<B_*C_*16,  256, 0, stream>>>(events, conv_w, beta, thr, zeropad, out);
}